// Round 1
// baseline (9479.745 us; speedup 1.0000x reference)
//
#include <hip/hip_runtime.h>
#include <hip/hip_bf16.h>
#include <math.h>

// Fixed problem dims
static constexpr int nB = 8, nT = 512, nE = 1024, nL = 8, nD = 512;
static constexpr int nBT = nB * nT;   // 4096 rows (b,t)
static constexpr int nLD = nL * nD;   // 4096

__device__ __forceinline__ float bf2f(unsigned short u) {
    return __uint_as_float(((unsigned int)u) << 16);
}
__device__ __forceinline__ unsigned short f2bf(float f) {
    unsigned int u = __float_as_uint(f);
    return (unsigned short)((u + 0x7fffu + ((u >> 16) & 1u)) >> 16);  // RNE
}
__device__ __forceinline__ float gelu_f(float x) {
    return 0.5f * x * (1.0f + erff(x * 0.70710678118654752f));  // exact GELU
}

// dst[r] = sum_i src[r,i] * (w ? w[i] : 1)
__global__ __launch_bounds__(256) void k_wdot(const float* __restrict__ src,
                                              const float* __restrict__ w,
                                              float* __restrict__ dst,
                                              int rows, int rowlen) {
    int row = blockIdx.x * 4 + (threadIdx.x >> 6);
    if (row >= rows) return;
    int lane = threadIdx.x & 63;
    const float* p = src + (size_t)row * rowlen;
    float s = 0.f;
    if (w) { for (int i = lane; i < rowlen; i += 64) s += p[i] * w[i]; }
    else   { for (int i = lane; i < rowlen; i += 64) s += p[i]; }
#pragma unroll
    for (int off = 32; off > 0; off >>= 1) s += __shfl_down(s, off, 64);
    if (lane == 0) dst[row] = s;
}

__global__ __launch_bounds__(256) void k_cvt(const float* __restrict__ src,
                                             unsigned short* __restrict__ dst, int n) {
    int idx = (blockIdx.x * 256 + threadIdx.x) * 4;
    if (idx + 3 >= n + 1) return;  // n divisible by 1024*4 anyway
    float4 v = *reinterpret_cast<const float4*>(src + idx);
    ushort4 o;
    o.x = f2bf(v.x); o.y = f2bf(v.y); o.z = f2bf(v.z); o.w = f2bf(v.w);
    *reinterpret_cast<ushort4*>(dst + idx) = o;
}

// C[m,n] = act( sum_k A[m,k]*B[k,n] + bias[n] ), 128x128 tile, BK=16, fp32
template<int ACT>
__global__ __launch_bounds__(256) void k_gemm(
    const float* __restrict__ A, int lda, long long sA,
    const float* __restrict__ Bm, int ldb, long long sB,
    const float* __restrict__ bias, long long sBias,
    float* __restrict__ C, int ldc, long long sC,
    int M, int N, int K)
{
    A  += (size_t)blockIdx.z * sA;
    Bm += (size_t)blockIdx.z * sB;
    C  += (size_t)blockIdx.z * sC;
    const float* biasp = bias ? bias + (size_t)blockIdx.z * sBias : nullptr;

    __shared__ __align__(16) float As[16][128];  // [k][m]
    __shared__ __align__(16) float Bs[16][128];  // [k][n]
    const int tid = threadIdx.x;
    const int tx = tid & 15, ty = tid >> 4;
    const int bm = blockIdx.y * 128, bn = blockIdx.x * 128;

    float acc[8][8];
#pragma unroll
    for (int i = 0; i < 8; ++i)
#pragma unroll
        for (int j = 0; j < 8; ++j) acc[i][j] = 0.f;

    const int arow = tid >> 1, ac8 = (tid & 1) * 8;
    const int brow = tid >> 4, bc8 = (tid & 15) * 8;

    for (int kt = 0; kt < K; kt += 16) {
        float4 a0 = *reinterpret_cast<const float4*>(A + (size_t)(bm + arow) * lda + kt + ac8);
        float4 a1 = *reinterpret_cast<const float4*>(A + (size_t)(bm + arow) * lda + kt + ac8 + 4);
        float4 b0 = *reinterpret_cast<const float4*>(Bm + (size_t)(kt + brow) * ldb + bn + bc8);
        float4 b1 = *reinterpret_cast<const float4*>(Bm + (size_t)(kt + brow) * ldb + bn + bc8 + 4);
        __syncthreads();  // previous tile's compute done before overwriting LDS
        As[ac8 + 0][arow] = a0.x; As[ac8 + 1][arow] = a0.y;
        As[ac8 + 2][arow] = a0.z; As[ac8 + 3][arow] = a0.w;
        As[ac8 + 4][arow] = a1.x; As[ac8 + 5][arow] = a1.y;
        As[ac8 + 6][arow] = a1.z; As[ac8 + 7][arow] = a1.w;
        *reinterpret_cast<float4*>(&Bs[brow][bc8]) = b0;
        *reinterpret_cast<float4*>(&Bs[brow][bc8 + 4]) = b1;
        __syncthreads();
#pragma unroll
        for (int kk = 0; kk < 16; ++kk) {
            float ar[8], br[8];
            *reinterpret_cast<float4*>(&ar[0]) = *reinterpret_cast<const float4*>(&As[kk][ty * 4]);
            *reinterpret_cast<float4*>(&ar[4]) = *reinterpret_cast<const float4*>(&As[kk][64 + ty * 4]);
            *reinterpret_cast<float4*>(&br[0]) = *reinterpret_cast<const float4*>(&Bs[kk][tx * 4]);
            *reinterpret_cast<float4*>(&br[4]) = *reinterpret_cast<const float4*>(&Bs[kk][64 + tx * 4]);
#pragma unroll
            for (int i = 0; i < 8; ++i)
#pragma unroll
                for (int j = 0; j < 8; ++j) acc[i][j] = fmaf(ar[i], br[j], acc[i][j]);
        }
    }
#pragma unroll
    for (int i = 0; i < 8; ++i) {
        int r = bm + (i >> 2) * 64 + ty * 4 + (i & 3);
#pragma unroll
        for (int jh = 0; jh < 2; ++jh) {
            int cb = bn + jh * 64 + tx * 4;
            float4 v = make_float4(acc[i][jh * 4 + 0], acc[i][jh * 4 + 1],
                                   acc[i][jh * 4 + 2], acc[i][jh * 4 + 3]);
            if (biasp) { v.x += biasp[cb]; v.y += biasp[cb + 1]; v.z += biasp[cb + 2]; v.w += biasp[cb + 3]; }
            if (ACT == 1) { v.x = gelu_f(v.x); v.y = gelu_f(v.y); v.z = gelu_f(v.z); v.w = gelu_f(v.w); }
            *reinterpret_cast<float4*>(C + (size_t)r * ldc + cb) = v;
        }
    }
}

// One WG per (b,l) recurrence. blockIdx%8 = layer -> same-layer WGs share an XCD L2.
__global__ __launch_bounds__(256) void k_scan(
    const float* __restrict__ tokens,          // [B,T,L,D]
    const unsigned short* __restrict__ wbf,    // [L,D,2D] bf16
    const float* __restrict__ glu_b,           // [L,2D]
    const float* __restrict__ sc_sum, const float* __restrict__ ii_sum,  // [L,D]
    const float* __restrict__ ln_glu_g, const float* __restrict__ ln_glu_b,
    const float* __restrict__ ln_state_g, const float* __restrict__ ln_state_b,
    float* __restrict__ states)                // [B,T,L,D]
{
    const int l = blockIdx.x & 7;
    const int b = blockIdx.x >> 3;
    __shared__ __align__(16) float s_state[nD], s_hn[nD], s_proj[2 * nD];
    __shared__ __align__(16) float s_sc[nD], s_ii[nD], s_gb[2 * nD];
    __shared__ __align__(16) float s_lgg[nD], s_lgb[nD], s_lsg[nD], s_lsb[nD];
    __shared__ float red[8];
    const int tid = threadIdx.x;
    for (int i = tid; i < nD; i += 256) {
        s_sc[i] = sc_sum[l * nD + i];
        s_ii[i] = ii_sum[l * nD + i];
        s_lgg[i] = ln_glu_g[i]; s_lgb[i] = ln_glu_b[i];
        s_lsg[i] = ln_state_g[i]; s_lsb[i] = ln_state_b[i];
        s_state[i] = 0.f;
    }
    for (int i = tid; i < 2 * nD; i += 256) s_gb[i] = glu_b[l * 2 * nD + i];
    __syncthreads();

    const unsigned short* wl = wbf + (size_t)l * nD * (2 * nD);
    const int wid = tid >> 6, lane = tid & 63;
    const int d0 = tid * 2;

    for (int t = 0; t < nT; ++t) {
        // phase A: h = state*sc + tok*ii ; LN -> s_hn
        const float* tok = tokens + (((size_t)b * nT + t) * nL + l) * nD;
        float2 tk = *reinterpret_cast<const float2*>(tok + d0);
        float h0 = s_state[d0] * s_sc[d0] + tk.x * s_ii[d0];
        float h1 = s_state[d0 + 1] * s_sc[d0 + 1] + tk.y * s_ii[d0 + 1];
        float sum = h0 + h1, sq = h0 * h0 + h1 * h1;
#pragma unroll
        for (int off = 32; off > 0; off >>= 1) {
            sum += __shfl_down(sum, off, 64); sq += __shfl_down(sq, off, 64);
        }
        if (lane == 0) { red[wid] = sum; red[4 + wid] = sq; }
        __syncthreads();
        sum = red[0] + red[1] + red[2] + red[3];
        sq  = red[4] + red[5] + red[6] + red[7];
        float mean = sum * (1.f / nD);
        float inv = rsqrtf(sq * (1.f / nD) - mean * mean + 1e-5f);
        s_hn[d0]     = (h0 - mean) * inv * s_lgg[d0]     + s_lgb[d0];
        s_hn[d0 + 1] = (h1 - mean) * inv * s_lgg[d0 + 1] + s_lgb[d0 + 1];
        __syncthreads();

        // phase B: proj = hn @ glu_w[l] + glu_b[l]; thread owns 4 contiguous cols
        const int c = tid * 4;
        float a0 = s_gb[c], a1 = s_gb[c + 1], a2 = s_gb[c + 2], a3 = s_gb[c + 3];
        const unsigned short* wp = wl + c;
#pragma unroll 4
        for (int k0 = 0; k0 < nD; k0 += 4) {
            float4 h4 = *reinterpret_cast<const float4*>(&s_hn[k0]);
            ushort4 w0 = *reinterpret_cast<const ushort4*>(wp + (size_t)(k0 + 0) * 1024);
            ushort4 w1 = *reinterpret_cast<const ushort4*>(wp + (size_t)(k0 + 1) * 1024);
            ushort4 w2 = *reinterpret_cast<const ushort4*>(wp + (size_t)(k0 + 2) * 1024);
            ushort4 w3 = *reinterpret_cast<const ushort4*>(wp + (size_t)(k0 + 3) * 1024);
            a0 += h4.x * bf2f(w0.x) + h4.y * bf2f(w1.x) + h4.z * bf2f(w2.x) + h4.w * bf2f(w3.x);
            a1 += h4.x * bf2f(w0.y) + h4.y * bf2f(w1.y) + h4.z * bf2f(w2.y) + h4.w * bf2f(w3.y);
            a2 += h4.x * bf2f(w0.z) + h4.y * bf2f(w1.z) + h4.z * bf2f(w2.z) + h4.w * bf2f(w3.z);
            a3 += h4.x * bf2f(w0.w) + h4.y * bf2f(w1.w) + h4.z * bf2f(w2.w) + h4.w * bf2f(w3.w);
        }
        *reinterpret_cast<float4*>(&s_proj[c]) = make_float4(a0, a1, a2, a3);
        __syncthreads();

        // phase C: v = a*sigmoid(g); LN -> new state; write out
        float pa0 = s_proj[d0],     pg0 = s_proj[d0 + nD];
        float pa1 = s_proj[d0 + 1], pg1 = s_proj[d0 + 1 + nD];
        float v0 = pa0 / (1.f + __expf(-pg0));
        float v1 = pa1 / (1.f + __expf(-pg1));
        sum = v0 + v1; sq = v0 * v0 + v1 * v1;
#pragma unroll
        for (int off = 32; off > 0; off >>= 1) {
            sum += __shfl_down(sum, off, 64); sq += __shfl_down(sq, off, 64);
        }
        if (lane == 0) { red[wid] = sum; red[4 + wid] = sq; }
        __syncthreads();
        sum = red[0] + red[1] + red[2] + red[3];
        sq  = red[4] + red[5] + red[6] + red[7];
        mean = sum * (1.f / nD);
        inv = rsqrtf(sq * (1.f / nD) - mean * mean + 1e-5f);
        float n0 = (v0 - mean) * inv * s_lsg[d0]     + s_lsb[d0];
        float n1 = (v1 - mean) * inv * s_lsg[d0 + 1] + s_lsb[d0 + 1];
        s_state[d0] = n0; s_state[d0 + 1] = n1;
        *reinterpret_cast<float2*>(states + (((size_t)b * nT + t) * nL + l) * nD + d0) =
            make_float2(n0, n1);
        __syncthreads();
    }
}

// y = LN(states * os_sum[l]) with ff_ln params; one wave per row
__global__ __launch_bounds__(256) void k_y(
    const float* __restrict__ states, const float* __restrict__ os_sum,
    const float* __restrict__ fg, const float* __restrict__ fb,
    float* __restrict__ y)
{
    const int row = blockIdx.x * 4 + (threadIdx.x >> 6);
    const int lane = threadIdx.x & 63;
    const int l = row & 7;
    const float* sp = states + (size_t)row * nD;
    const float* op = os_sum + l * nD;
    const int base = lane * 8;
    float v[8];
    float sum = 0.f, sq = 0.f;
#pragma unroll
    for (int j = 0; j < 8; j += 4) {
        float4 s4 = *reinterpret_cast<const float4*>(sp + base + j);
        float4 o4 = *reinterpret_cast<const float4*>(op + base + j);
        v[j] = s4.x * o4.x; v[j + 1] = s4.y * o4.y; v[j + 2] = s4.z * o4.z; v[j + 3] = s4.w * o4.w;
    }
#pragma unroll
    for (int j = 0; j < 8; ++j) { sum += v[j]; sq += v[j] * v[j]; }
#pragma unroll
    for (int off = 32; off > 0; off >>= 1) {
        sum += __shfl_xor(sum, off, 64); sq += __shfl_xor(sq, off, 64);
    }
    float mean = sum * (1.f / nD);
    float inv = rsqrtf(sq * (1.f / nD) - mean * mean + 1e-5f);
    const float* gp = fg + l * nD;
    const float* bp = fb + l * nD;
    float* yp = y + (size_t)row * nD;
#pragma unroll
    for (int j = 0; j < 8; j += 4) {
        float4 g4 = *reinterpret_cast<const float4*>(gp + base + j);
        float4 b4 = *reinterpret_cast<const float4*>(bp + base + j);
        float4 o;
        o.x = (v[j]     - mean) * inv * g4.x + b4.x;
        o.y = (v[j + 1] - mean) * inv * g4.y + b4.y;
        o.z = (v[j + 2] - mean) * inv * g4.z + b4.z;
        o.w = (v[j + 3] - mean) * inv * g4.w + b4.w;
        *reinterpret_cast<float4*>(yp + base + j) = o;
    }
}

// scores from h via w2a; softmax over L; scale h in place; store probs
__global__ __launch_bounds__(256) void k_scores(
    float* __restrict__ h, const float* __restrict__ w2a,
    const float* __restrict__ c2, const float* __restrict__ attn_b,
    float* __restrict__ scores)
{
    const int bt = blockIdx.x;
    const int tid = threadIdx.x, wid = tid >> 6, lane = tid & 63;
    __shared__ float slog[nL];
    float* hrow = h + (size_t)bt * nLD;
    for (int l = wid; l < nL; l += 4) {
        const float* hp = hrow + l * nD;
        const float* wp = w2a + l * nD;
        float s = 0.f;
        for (int i = lane; i < nD; i += 64) s += hp[i] * wp[i];
#pragma unroll
        for (int off = 32; off > 0; off >>= 1) s += __shfl_down(s, off, 64);
        if (lane == 0) slog[l] = s + c2[l] + attn_b[0];
    }
    __syncthreads();
    float mx = -1e30f;
#pragma unroll
    for (int l = 0; l < nL; ++l) mx = fmaxf(mx, slog[l]);
    float den = 0.f;
#pragma unroll
    for (int l = 0; l < nL; ++l) den += __expf(slog[l] - mx);
    float rden = 1.f / den;
#pragma unroll
    for (int it = 0; it < 4; ++it) {
        int idx = tid * 4 + it * 1024;
        int l = idx >> 9;
        float s = __expf(slog[l] - mx) * rden;
        float4 v = *reinterpret_cast<float4*>(hrow + idx);
        v.x *= s; v.y *= s; v.z *= s; v.w *= s;
        *reinterpret_cast<float4*>(hrow + idx) = v;
    }
    if (tid < nL) scores[bt * nL + tid] = __expf(slog[tid] - mx) * rden;
}

// out = LN( wbuf + sum_l s_l * ff_b2[l] ) with ln_emb params
__global__ __launch_bounds__(256) void k_final(
    const float* __restrict__ wbuf, const float* __restrict__ scores,
    const float* __restrict__ ff_b2, const float* __restrict__ g,
    const float* __restrict__ bvec, float* __restrict__ out)
{
    const int bt = blockIdx.x;
    const int tid = threadIdx.x;
    __shared__ float ssc[nL];
    __shared__ float red[8];
    if (tid < nL) ssc[tid] = scores[bt * nL + tid];
    __syncthreads();
    const int e0 = tid * 4;
    float4 w = *reinterpret_cast<const float4*>(wbuf + (size_t)bt * nE + e0);
#pragma unroll
    for (int l = 0; l < nL; ++l) {
        float s = ssc[l];
        float4 b2 = *reinterpret_cast<const float4*>(ff_b2 + l * nE + e0);
        w.x += s * b2.x; w.y += s * b2.y; w.z += s * b2.z; w.w += s * b2.w;
    }
    float sum = w.x + w.y + w.z + w.w;
    float sq = w.x * w.x + w.y * w.y + w.z * w.z + w.w * w.w;
    int wid = tid >> 6, lane = tid & 63;
#pragma unroll
    for (int off = 32; off > 0; off >>= 1) {
        sum += __shfl_down(sum, off, 64); sq += __shfl_down(sq, off, 64);
    }
    if (lane == 0) { red[wid] = sum; red[4 + wid] = sq; }
    __syncthreads();
    sum = red[0] + red[1] + red[2] + red[3];
    sq  = red[4] + red[5] + red[6] + red[7];
    float mean = sum * (1.f / nE);
    float inv = rsqrtf(sq * (1.f / nE) - mean * mean + 1e-5f);
    float4 g4 = *reinterpret_cast<const float4*>(g + e0);
    float4 b4 = *reinterpret_cast<const float4*>(bvec + e0);
    float4 o;
    o.x = (w.x - mean) * inv * g4.x + b4.x;
    o.y = (w.y - mean) * inv * g4.y + b4.y;
    o.z = (w.z - mean) * inv * g4.z + b4.z;
    o.w = (w.w - mean) * inv * g4.w + b4.w;
    *reinterpret_cast<float4*>(out + (size_t)bt * nE + e0) = o;
}

extern "C" void kernel_launch(void* const* d_in, const int* in_sizes, int n_in,
                              void* d_out, int out_size, void* d_ws, size_t ws_size,
                              hipStream_t stream) {
    (void)in_sizes; (void)n_in; (void)out_size; (void)ws_size;
    const float* emb            = (const float*)d_in[0];
    const float* state_control  = (const float*)d_in[1];
    const float* input_influence= (const float*)d_in[2];
    const float* output_shaper  = (const float*)d_in[3];
    const float* glu_w          = (const float*)d_in[4];
    const float* glu_b          = (const float*)d_in[5];
    const float* e2s_w          = (const float*)d_in[6];
    const float* e2s_b          = (const float*)d_in[7];
    const float* ln_glu_g       = (const float*)d_in[8];
    const float* ln_glu_b       = (const float*)d_in[9];
    const float* ln_state_g     = (const float*)d_in[10];
    const float* ln_state_b     = (const float*)d_in[11];
    const float* ln_emb_g       = (const float*)d_in[12];
    const float* ln_emb_b       = (const float*)d_in[13];
    const float* ff_ln_g        = (const float*)d_in[14];
    const float* ff_ln_b        = (const float*)d_in[15];
    const float* ff_w1          = (const float*)d_in[16];
    const float* ff_b1          = (const float*)d_in[17];
    const float* ff_w2          = (const float*)d_in[18];
    const float* ff_b2          = (const float*)d_in[19];
    const float* attn_w         = (const float*)d_in[20];
    const float* attn_b         = (const float*)d_in[21];

    // workspace layout (~143 MB)
    char* ws = (char*)d_ws;
    float* tokens = (float*)ws;            ws += (size_t)nBT * nLD * 4;   // 67 MB (later: y, then wbuf)
    float* states = (float*)ws;            ws += (size_t)nBT * nLD * 4;   // 67 MB (later: h)
    unsigned short* wbf = (unsigned short*)ws; ws += (size_t)nL * nD * 2 * nD * 2;  // 8.4 MB
    float* sc_sum = (float*)ws;            ws += nLD * 4;
    float* ii_sum = (float*)ws;            ws += nLD * 4;
    float* os_sum = (float*)ws;            ws += nLD * 4;
    float* w2a    = (float*)ws;            ws += nLD * 4;
    float* c2     = (float*)ws;            ws += 256;
    float* scores = (float*)ws;            ws += (size_t)nBT * nL * 4;
    float* wbuf = tokens;  // alias: tokens (y) dead after ff1 GEMM

    // precompute
    k_cvt<<<4096, 256, 0, stream>>>(glu_w, wbf, nL * nD * 2 * nD);
    k_wdot<<<1024, 256, 0, stream>>>(state_control, nullptr, sc_sum, nLD, nD);
    k_wdot<<<1024, 256, 0, stream>>>(input_influence, nullptr, ii_sum, nLD, nD);
    k_wdot<<<1024, 256, 0, stream>>>(output_shaper, nullptr, os_sum, nLD, nD);
    k_wdot<<<1024, 256, 0, stream>>>(ff_w2, attn_w, w2a, nLD, nE);
    k_wdot<<<2, 256, 0, stream>>>(ff_b2, attn_w, c2, nL, nE);

    // tokens = emb @ e2s_w + e2s_b   [4096 x 4096], K=1024
    k_gemm<0><<<dim3(32, 32, 1), 256, 0, stream>>>(
        emb, nE, 0, e2s_w, nLD, 0, e2s_b, 0, tokens, nLD, 0, nBT, nLD, nE);

    // recurrent scan -> states
    k_scan<<<64, 256, 0, stream>>>(tokens, wbf, glu_b, sc_sum, ii_sum,
                                   ln_glu_g, ln_glu_b, ln_state_g, ln_state_b, states);

    // y = LN(states * os_sum)  (into tokens buffer)
    k_y<<<nBT * nL / 4, 256, 0, stream>>>(states, os_sum, ff_ln_g, ff_ln_b, tokens);

    // h = GELU(y @ ff_w1 + ff_b1), per-layer batched  (into states buffer)
    k_gemm<1><<<dim3(4, 32, 8), 256, 0, stream>>>(
        tokens, nLD, nD, ff_w1, nD, (long long)nD * nD, ff_b1, nD,
        states, nLD, nD, nBT, nD, nD);

    // scores + scale h in place
    k_scores<<<nBT, 256, 0, stream>>>(states, w2a, c2, attn_b, scores);

    // weighted = (s*h) @ W2cat   [4096 x 1024], K=4096  (into wbuf=tokens)
    k_gemm<0><<<dim3(8, 32, 1), 256, 0, stream>>>(
        states, nLD, 0, ff_w2, nE, 0, nullptr, 0, wbuf, nE, 0, nBT, nE, nLD);

    // out = LN(weighted + sum_l s_l*ff_b2[l])
    k_final<<<nBT, 256, 0, stream>>>(wbuf, scores, ff_b2, ln_emb_g, ln_emb_b, (float*)d_out);
}